// Round 6
// baseline (193.476 us; speedup 1.0000x reference)
//
#include <hip/hip_runtime.h>
#include <hip/hip_bf16.h>
#include <cstdint>

namespace {
constexpr int NB     = 256;   // batches
constexpr int LQ     = 50;
constexpr int LK     = 200;
constexpr int DIM    = 128;
constexpr int NWAVE  = 8;
constexpr int NTHR   = NWAVE * 64;
constexpr int QSPLIT = 2;             // grid = 512; two co-resident blocks per CU
constexpr int QBLK   = LQ / QSPLIT;   // 25 q rows per block
constexpr int LSTR   = 204;   // weights row stride (multiple of 4 -> float4 reads)
constexpr int KSTR   = 136;   // bf16 K row stride in elements (272 B, 16B-aligned rows)
constexpr int NKR    = 208;   // staged K rows (13 n-tiles x 16)
constexpr int VG     = 8;     // V-rows per gather group (phase 3 MLP depth)
constexpr int NG     = LK / VG;      // 25 groups
constexpr int KPW    = LK / NWAVE;   // (bf16 fallback path only)
}

typedef __attribute__((ext_vector_type(8))) short bf16x8;   // 8 bf16 = 4 VGPR
typedef __attribute__((ext_vector_type(4))) float f32x4;

__device__ __forceinline__ float bflo(uint32_t u) { return __uint_as_float(u << 16); }
__device__ __forceinline__ float bfhi(uint32_t u) { return __uint_as_float(u & 0xFFFF0000u); }
__device__ __forceinline__ uint32_t f2bf(float f) {
    uint32_t x = __float_as_uint(f);
    return (x + 0x7FFFu + ((x >> 16) & 1u)) >> 16;   // RNE
}

// ---------------------------------------------------------------------------
// f32 path — THE path that executes on this dataset.
// R6: q-split grid (512 blocks) + LDS cut to 77.8 KB -> 2 blocks/CU, so two
// blocks' phases mutually hide latency (R5 post-mortem: 75% of wall = exposed
// latency at 1 block/CU). Q-frags now staged global->registers (qsh removed);
// weights buffer is 25 rows. Same-batch halves mapped to the same XCD.
// ---------------------------------------------------------------------------
__device__ __forceinline__ void run_f32(
    int b, int q0,
    const int* __restrict__ Qi, const int* __restrict__ Ki, const int* __restrict__ Vi,
    const void* __restrict__ Wq, const void* __restrict__ Wk, const void* __restrict__ Wv,
    const void* __restrict__ gm, const void* __restrict__ bt, const void* __restrict__ ep,
    void* __restrict__ out, float* __restrict__ wgt,
    uint16_t* __restrict__ ksh, int* __restrict__ vix)
{
    const int tid  = threadIdx.x;
    const int w    = tid >> 6;
    const int lane = tid & 63;
    const int l15  = lane & 15;
    const int g    = lane >> 4;      // k-group 0..3
    const int m    = w >> 2;         // m-tile 0..1 (local q rows m*16..m*16+15)

    // ---- phase 0: stage V idx + K rows (bf16, coalesced); Q-frags to regs -----
    for (int i = tid; i < LK; i += NTHR) vix[i] = Vi[b * LK + i];

    #pragma unroll
    for (int j = 0; j < NKR / NWAVE; ++j) {        // 26 K rows per wave
        const int r = w + NWAVE * j;
        uint32_t v = 0u;
        if (r < LK) {
            const int kidx = Ki[b * LK + r];
            const float2 f = ((const float2*)((const float*)Wk + (size_t)kidx * DIM))[lane];
            v = f2bf(f.x) | (f2bf(f.y) << 16);
        }
        *(uint32_t*)(ksh + (size_t)r * KSTR + 2 * lane) = v;
    }

    bf16x8 afr[4];                                 // A-frags direct from global
    {
        const int ql   = m * 16 + l15;             // local q row 0..31
        const int qc   = (ql < QBLK) ? ql : (QBLK - 1);
        const int qidx = Qi[b * LQ + q0 + qc];
        const float* qrow = (const float*)Wq + (size_t)qidx * DIM + g * 8;
        #pragma unroll
        for (int ks = 0; ks < 4; ++ks) {
            const float4 f0 = *(const float4*)(qrow + ks * 32);
            const float4 f1 = *(const float4*)(qrow + ks * 32 + 4);
            union { bf16x8 v; uint16_t u[8]; } pk;
            pk.u[0] = (uint16_t)f2bf(f0.x); pk.u[1] = (uint16_t)f2bf(f0.y);
            pk.u[2] = (uint16_t)f2bf(f0.z); pk.u[3] = (uint16_t)f2bf(f0.w);
            pk.u[4] = (uint16_t)f2bf(f1.x); pk.u[5] = (uint16_t)f2bf(f1.y);
            pk.u[6] = (uint16_t)f2bf(f1.z); pk.u[7] = (uint16_t)f2bf(f1.w);
            afr[ks] = pk.v;
        }
    }
    __syncthreads();

    // ---- phase 1: logits = Q @ K^T via mfma_f32_16x16x32_bf16 ------------------
    // D col=lane&15, row=(lane>>4)*4+reg  [m89-verified mapping, proven in R5].
    {
        #pragma unroll 1
        for (int n = (w & 3); n < 13; n += 4) {    // 3-4 n-tiles per wave
            const uint16_t* kbase = ksh + (size_t)(n * 16 + l15) * KSTR + g * 8;
            f32x4 acc = {0.f, 0.f, 0.f, 0.f};
            #pragma unroll
            for (int ks = 0; ks < 4; ++ks) {
                const bf16x8 bfr = *(const bf16x8*)(kbase + ks * 32);
                acc = __builtin_amdgcn_mfma_f32_16x16x32_bf16(afr[ks], bfr, acc, 0, 0, 0);
            }
            const int kcol = n * 16 + l15;
            #pragma unroll
            for (int r = 0; r < 4; ++r) {
                const int ql = m * 16 + g * 4 + r;
                if (ql < QBLK && kcol < LK)
                    wgt[ql * LSTR + kcol] = acc[r] * 0.08838834764831843f;  // 1/sqrt(128)
            }
        }
    }
    __syncthreads();

    // ---- phase 2: weight = softmax_k(logit + eps)  (exact algebra) -------------
    for (int q = w; q < QBLK; q += NWAVE) {        // 3-4 rows per wave
        float z[4];
        float mx = -INFINITY;
        #pragma unroll
        for (int i = 0; i < 4; ++i) {
            const int k = i * 64 + lane;
            if (k < LK) {
                const float e = ((const float*)ep)[(size_t)(b * LQ + q0 + q) * LK + k];
                z[i] = wgt[q * LSTR + k] + e;
                mx = fmaxf(mx, z[i]);
            } else z[i] = -INFINITY;
        }
        #pragma unroll
        for (int off = 32; off > 0; off >>= 1) mx = fmaxf(mx, __shfl_xor(mx, off));
        float e4[4]; float s = 0.f;
        #pragma unroll
        for (int i = 0; i < 4; ++i) {
            e4[i] = (i * 64 + lane < LK) ? __expf(z[i] - mx) : 0.f;
            s += e4[i];
        }
        #pragma unroll
        for (int off = 32; off > 0; off >>= 1) s += __shfl_xor(s, off);
        const float inv = 1.0f / s;
        #pragma unroll
        for (int i = 0; i < 4; ++i) {
            const int k = i * 64 + lane;
            if (k < LK) wgt[q * LSTR + k] = e4[i] * inv;
        }
    }
    __syncthreads();

    // ---- phase 3: context (lane = d-pair) + layernorm --------------------------
    // 8-deep double-buffered V gather; weights as float4 wave-uniform broadcasts.
    float c0[4], c1[4];
    #pragma unroll
    for (int qi = 0; qi < 4; ++qi) { c0[qi] = 0.f; c1[qi] = 0.f; }

    int rowq[4];
    #pragma unroll
    for (int qi = 0; qi < 4; ++qi) {
        const int q = w + 8 * qi;
        rowq[qi] = (q < QBLK) ? q : (QBLK - 1);    // wave-uniform cap (dead slots)
    }

    const float* Wvf = (const float*)Wv;

    auto load_grp = [&](float2 (&f)[VG], int kg) {
        const int4 ia = *(const int4*)(vix + kg * VG);
        const int4 ib = *(const int4*)(vix + kg * VG + 4);
        f[0] = ((const float2*)(Wvf + (size_t)ia.x * DIM))[lane];
        f[1] = ((const float2*)(Wvf + (size_t)ia.y * DIM))[lane];
        f[2] = ((const float2*)(Wvf + (size_t)ia.z * DIM))[lane];
        f[3] = ((const float2*)(Wvf + (size_t)ia.w * DIM))[lane];
        f[4] = ((const float2*)(Wvf + (size_t)ib.x * DIM))[lane];
        f[5] = ((const float2*)(Wvf + (size_t)ib.y * DIM))[lane];
        f[6] = ((const float2*)(Wvf + (size_t)ib.z * DIM))[lane];
        f[7] = ((const float2*)(Wvf + (size_t)ib.w * DIM))[lane];
    };
    auto consume_grp = [&](const float2 (&f)[VG], int kg) {
        #pragma unroll
        for (int qi = 0; qi < 4; ++qi) {
            const float4 wa = *(const float4*)(wgt + rowq[qi] * LSTR + kg * VG);
            const float4 wb = *(const float4*)(wgt + rowq[qi] * LSTR + kg * VG + 4);
            c0[qi] = fmaf(wa.x, f[0].x, c0[qi]); c1[qi] = fmaf(wa.x, f[0].y, c1[qi]);
            c0[qi] = fmaf(wa.y, f[1].x, c0[qi]); c1[qi] = fmaf(wa.y, f[1].y, c1[qi]);
            c0[qi] = fmaf(wa.z, f[2].x, c0[qi]); c1[qi] = fmaf(wa.z, f[2].y, c1[qi]);
            c0[qi] = fmaf(wa.w, f[3].x, c0[qi]); c1[qi] = fmaf(wa.w, f[3].y, c1[qi]);
            c0[qi] = fmaf(wb.x, f[4].x, c0[qi]); c1[qi] = fmaf(wb.x, f[4].y, c1[qi]);
            c0[qi] = fmaf(wb.y, f[5].x, c0[qi]); c1[qi] = fmaf(wb.y, f[5].y, c1[qi]);
            c0[qi] = fmaf(wb.z, f[6].x, c0[qi]); c1[qi] = fmaf(wb.z, f[6].y, c1[qi]);
            c0[qi] = fmaf(wb.w, f[7].x, c0[qi]); c1[qi] = fmaf(wb.w, f[7].y, c1[qi]);
        }
    };

    float2 fA[VG], fB[VG];
    load_grp(fA, 0);
    #pragma unroll 1
    for (int kg = 0; kg < NG - 1; kg += 2) {   // kg = 0,2,...,22  (NG = 25)
        load_grp(fB, kg + 1);
        consume_grp(fA, kg);
        load_grp(fA, kg + 2);                  // kg+2 <= 24 always in range
        consume_grp(fB, kg + 1);
    }
    consume_grp(fA, NG - 1);

    const float2 gf = ((const float2*)gm)[lane];
    const float2 bf = ((const float2*)bt)[lane];

    #pragma unroll
    for (int qi = 0; qi < 4; ++qi) {
        const int q = w + 8 * qi;
        if (q < QBLK) {                    // wave-uniform
            float s1 = c0[qi] + c1[qi];
            float s2 = c0[qi] * c0[qi] + c1[qi] * c1[qi];
            #pragma unroll
            for (int off = 32; off > 0; off >>= 1) {
                s1 += __shfl_xor(s1, off);
                s2 += __shfl_xor(s2, off);
            }
            const float mu = s1 * (1.0f / DIM);
            float var = s2 * (1.0f / DIM) - mu * mu;
            var = fmaxf(var, 0.f);
            const float rs = rsqrtf(var + 1e-5f);
            float2 o;
            o.x = (c0[qi] - mu) * rs * gf.x + bf.x;
            o.y = (c1[qi] - mu) * rs * gf.y + bf.y;
            ((float2*)out)[(size_t)(b * LQ + q0 + q) * (DIM / 2) + lane] = o;
        }
    }
}

// ---------------------------------------------------------------------------
// bf16 path — retained for probe completeness (not executed on this dataset).
// q-split-aware VALU dot-product; fits the 25-row weights buffer.
// ---------------------------------------------------------------------------
__device__ __forceinline__ void run_bf16(
    int b, int q0,
    const int* __restrict__ Qi, const int* __restrict__ Ki, const int* __restrict__ Vi,
    const void* __restrict__ Wq, const void* __restrict__ Wk, const void* __restrict__ Wv,
    const void* __restrict__ gm, const void* __restrict__ bt, const void* __restrict__ ep,
    void* __restrict__ out, float* __restrict__ wgt, int* __restrict__ vix)
{
    const int tid  = threadIdx.x;
    const int w    = tid >> 6;
    const int lane = tid & 63;

    for (int i = tid; i < LK; i += NTHR) vix[i] = Vi[b * LK + i];

    {
        const int ql   = (lane < QBLK) ? lane : (QBLK - 1);
        const int qidx = Qi[b * LQ + q0 + ql];
        const uint4* qrow = (const uint4*)((const uint16_t*)Wq + (size_t)qidx * DIM);
        const int k0 = w * KPW;

        int kidx[KPW];
        #pragma unroll
        for (int kk = 0; kk < KPW; ++kk) kidx[kk] = Ki[b * LK + k0 + kk];
        float acc[KPW];
        #pragma unroll
        for (int kk = 0; kk < KPW; ++kk) acc[kk] = 0.f;

        #pragma unroll 1
        for (int h = 0; h < DIM / 8; ++h) {
            const uint4 qc = qrow[h];
            const float a0 = bflo(qc.x), a1 = bfhi(qc.x);
            const float a2 = bflo(qc.y), a3 = bfhi(qc.y);
            const float a4 = bflo(qc.z), a5 = bfhi(qc.z);
            const float a6 = bflo(qc.w), a7 = bfhi(qc.w);
            #pragma unroll
            for (int kk = 0; kk < KPW; ++kk) {
                const uint4 t = ((const uint4*)((const uint16_t*)Wk + (size_t)kidx[kk] * DIM))[h];
                float a = acc[kk];
                a = fmaf(a0, bflo(t.x), a);
                a = fmaf(a1, bfhi(t.x), a);
                a = fmaf(a2, bflo(t.y), a);
                a = fmaf(a3, bfhi(t.y), a);
                a = fmaf(a4, bflo(t.z), a);
                a = fmaf(a5, bfhi(t.z), a);
                a = fmaf(a6, bflo(t.w), a);
                a = fmaf(a7, bfhi(t.w), a);
                acc[kk] = a;
            }
        }
        if (lane < QBLK) {
            #pragma unroll
            for (int kk = 0; kk < KPW; ++kk)
                wgt[lane * LSTR + (k0 + kk)] = acc[kk] * 0.08838834764831843f;
        }
    }
    __syncthreads();

    for (int q = w; q < QBLK; q += NWAVE) {
        float z[4];
        float mx = -INFINITY;
        #pragma unroll
        for (int i = 0; i < 4; ++i) {
            const int k = i * 64 + lane;
            if (k < LK) {
                const float e = bflo((uint32_t)((const uint16_t*)ep)[(size_t)(b*LQ+q0+q)*LK + k]);
                z[i] = wgt[q * LSTR + k] + e;
                mx = fmaxf(mx, z[i]);
            } else z[i] = -INFINITY;
        }
        #pragma unroll
        for (int off = 32; off > 0; off >>= 1) mx = fmaxf(mx, __shfl_xor(mx, off));
        float e4[4]; float s = 0.f;
        #pragma unroll
        for (int i = 0; i < 4; ++i) {
            e4[i] = (i * 64 + lane < LK) ? __expf(z[i] - mx) : 0.f;
            s += e4[i];
        }
        #pragma unroll
        for (int off = 32; off > 0; off >>= 1) s += __shfl_xor(s, off);
        const float inv = 1.0f / s;
        #pragma unroll
        for (int i = 0; i < 4; ++i) {
            const int k = i * 64 + lane;
            if (k < LK) wgt[q * LSTR + k] = e4[i] * inv;
        }
    }
    __syncthreads();

    float c0[4], c1[4];
    #pragma unroll
    for (int qi = 0; qi < 4; ++qi) { c0[qi] = 0.f; c1[qi] = 0.f; }

    int rowq[4];
    #pragma unroll
    for (int qi = 0; qi < 4; ++qi) {
        const int q = w + 8 * qi;
        rowq[qi] = (q < QBLK) ? q : (QBLK - 1);
    }

    const uint16_t* Wvh = (const uint16_t*)Wv;

    auto load_grp = [&](uint32_t (&f)[VG], int kg) {
        #pragma unroll
        for (int u = 0; u < VG; ++u) {
            const int vidx = vix[kg * VG + u];
            f[u] = ((const uint32_t*)(Wvh + (size_t)vidx * DIM))[lane];
        }
    };
    auto consume_grp = [&](const uint32_t (&f)[VG], int kg) {
        #pragma unroll
        for (int u = 0; u < VG; ++u) {
            const int k = kg * VG + u;
            const float v0 = bflo(f[u]), v1 = bfhi(f[u]);
            #pragma unroll
            for (int qi = 0; qi < 4; ++qi) {
                const float wt = wgt[rowq[qi] * LSTR + k];
                c0[qi] = fmaf(wt, v0, c0[qi]);
                c1[qi] = fmaf(wt, v1, c1[qi]);
            }
        }
    };

    uint32_t fA[VG], fB[VG];
    load_grp(fA, 0);
    #pragma unroll 1
    for (int kg = 0; kg < NG - 1; kg += 2) {
        load_grp(fB, kg + 1);
        consume_grp(fA, kg);
        load_grp(fA, kg + 2);
        consume_grp(fB, kg + 1);
    }
    consume_grp(fA, NG - 1);

    const uint32_t gu = ((const uint32_t*)gm)[lane];
    const uint32_t bu = ((const uint32_t*)bt)[lane];
    const float g0 = bflo(gu), g1 = bfhi(gu);
    const float be0 = bflo(bu), be1 = bfhi(bu);

    #pragma unroll
    for (int qi = 0; qi < 4; ++qi) {
        const int q = w + 8 * qi;
        if (q < QBLK) {
            float s1 = c0[qi] + c1[qi];
            float s2 = c0[qi]*c0[qi] + c1[qi]*c1[qi];
            #pragma unroll
            for (int off = 32; off > 0; off >>= 1) {
                s1 += __shfl_xor(s1, off);
                s2 += __shfl_xor(s2, off);
            }
            const float mu = s1 * (1.0f / DIM);
            float var = s2 * (1.0f / DIM) - mu * mu;
            var = fmaxf(var, 0.f);
            const float rs = rsqrtf(var + 1e-5f);
            const float y0 = (c0[qi] - mu) * rs * g0 + be0;
            const float y1 = (c1[qi] - mu) * rs * g1 + be1;
            ((uint32_t*)out)[(size_t)(b*LQ+q0+q) * (DIM/2) + lane] = f2bf(y0) | (f2bf(y1) << 16);
        }
    }
}

__global__ __launch_bounds__(NTHR, 4) void fused_attn_ln(
    const int* __restrict__ Qi, const int* __restrict__ Ki, const int* __restrict__ Vi,
    const void* __restrict__ Wq, const void* __restrict__ Wk, const void* __restrict__ Wv,
    const void* __restrict__ gm, const void* __restrict__ bt, const void* __restrict__ ep,
    void* __restrict__ out)
{
    __shared__ __align__(16) float    wgt[QBLK * LSTR];  // 25x204 f32, 20.4 KB
    __shared__ __align__(16) uint16_t ksh[NKR * KSTR];   // 208 bf16 K rows, 56.6 KB
    __shared__ __align__(16) int      vix[LK];           // staged V indices, 0.8 KB
    // total 77.8 KB -> 2 blocks/CU (grid 512 over 256 CUs)

    // Same-batch halves on the same XCD: bb and bb+256 both map to xcd bb%8.
    const int bb = blockIdx.x;
    const int b  = bb & (NB - 1);
    const int q0 = (bb >> 8) * QBLK;

    // Dtype probe (same as all green rounds). On THIS dataset it selects f32.
    const uint32_t* probe = (const uint32_t*)Wq;
    int c = 0;
    #pragma unroll
    for (int i = 0; i < 64; ++i) {
        float f = bflo(probe[i]);
        c += (fabsf(f) < 1.0f) ? 1 : 0;
    }
    if (c >= 48) run_bf16(b, q0, Qi, Ki, Vi, Wq, Wk, Wv, gm, bt, ep, out, wgt, vix);
    else         run_f32 (b, q0, Qi, Ki, Vi, Wq, Wk, Wv, gm, bt, ep, out, wgt, ksh, vix);
}

extern "C" void kernel_launch(void* const* d_in, const int* in_sizes, int n_in,
                              void* d_out, int out_size, void* d_ws, size_t ws_size,
                              hipStream_t stream)
{
    (void)in_sizes; (void)n_in; (void)out_size; (void)d_ws; (void)ws_size;
    fused_attn_ln<<<NB * QSPLIT, NTHR, 0, stream>>>(
        (const int*)d_in[0], (const int*)d_in[1], (const int*)d_in[2],
        d_in[3], d_in[4], d_in[5], d_in[6], d_in[7], d_in[8], d_out);
}

// Round 7
// 177.376 us; speedup vs baseline: 1.0908x; 1.0908x over previous
//
#include <hip/hip_runtime.h>
#include <hip/hip_bf16.h>
#include <cstdint>

namespace {
constexpr int NB    = 256;   // batches; grid 256, 1 block/batch (R6 lesson: no dup staging)
constexpr int LQ    = 50;
constexpr int LK    = 200;
constexpr int DIM   = 128;
constexpr int NWAVE = 8;
constexpr int NTHR  = NWAVE * 64;
constexpr int LSTR  = 204;   // logits f32 row stride
constexpr int KSTR  = 136;   // ksh bf16 row stride (R5-proven)
constexpr int NKR   = 208;   // staged K rows (13 n-tiles x 16)
constexpr int PSTR  = 232;   // pwgt bf16 row stride (mult of 8 -> 16B-aligned b128 rows)
constexpr int VSTR  = 232;   // vsh  bf16 row stride (mult of 8)
constexpr int NKT3  = 7;     // phase-3 k-tiles (224 = 7*32, zero-padded 200..223)
constexpr int UKV   = 128 * VSTR;   // union region: max(208*136=28288, 128*232=29696)
constexpr int KPW   = LK / NWAVE;   // bf16 fallback path only
constexpr int VG    = 8;            // bf16 fallback path only
constexpr int NG    = LK / VG;      // bf16 fallback path only
}

typedef __attribute__((ext_vector_type(8))) short bf16x8;   // 8 bf16 = 4 VGPR
typedef __attribute__((ext_vector_type(4))) float f32x4;

__device__ __forceinline__ float bflo(uint32_t u) { return __uint_as_float(u << 16); }
__device__ __forceinline__ float bfhi(uint32_t u) { return __uint_as_float(u & 0xFFFF0000u); }
__device__ __forceinline__ uint32_t f2bf(float f) {
    uint32_t x = __float_as_uint(f);
    return (x + 0x7FFFu + ((x >> 16) & 1u)) >> 16;   // RNE
}

// ---------------------------------------------------------------------------
// f32 path — THE path that executes on this dataset.
// R7: phase 3 (context = P @ V) moved to MFMA. V staged TRANSPOSED in LDS
// (aliasing the dead ksh region): each lane's 8 row-loads already hold one
// d-column -> one b128 write, no shuffles. Weights stored bf16 (pwgt).
// Phase 3 drops from 1600 V-loads + 1600 ds_read_b128 + 12800 VALU FMA per
// block to 256 loads + ~280 b128 + 224 MFMA.  Phase 0/1/2 structure = R5.
// ---------------------------------------------------------------------------
__device__ __forceinline__ void run_f32(
    int b,
    const int* __restrict__ Qi, const int* __restrict__ Ki, const int* __restrict__ Vi,
    const void* __restrict__ Wq, const void* __restrict__ Wk, const void* __restrict__ Wv,
    const void* __restrict__ gm, const void* __restrict__ bt, const void* __restrict__ ep,
    void* __restrict__ out, float* __restrict__ lgt, uint16_t* __restrict__ ukv,
    uint16_t* __restrict__ pwgt, float2* __restrict__ part, int* __restrict__ vix)
{
    const int tid  = threadIdx.x;
    const int w    = tid >> 6;
    const int lane = tid & 63;
    const int l15  = lane & 15;
    const int g    = lane >> 4;      // k-group 0..3
    const int m    = w >> 1;         // m-tile 0..3 (q rows m*16..m*16+15)
    const int h    = w & 1;          // phase-1 n-parity / phase-3 d-half

    // ---- phase 0: stage V idx + K rows (bf16, coalesced); Q-frags to regs -----
    for (int i = tid; i < LK; i += NTHR) vix[i] = Vi[b * LK + i];

    uint16_t* ksh = ukv;             // K region (dies at end of phase 1)
    #pragma unroll
    for (int j = 0; j < NKR / NWAVE; ++j) {        // 26 K rows per wave
        const int r = w + NWAVE * j;
        uint32_t v = 0u;
        if (r < LK) {
            const int kidx = Ki[b * LK + r];
            const float2 f = ((const float2*)((const float*)Wk + (size_t)kidx * DIM))[lane];
            v = f2bf(f.x) | (f2bf(f.y) << 16);
        }
        *(uint32_t*)(ksh + (size_t)r * KSTR + 2 * lane) = v;
    }

    bf16x8 afr[4];                                 // Q A-frags direct from global
    {
        const int ql   = m * 16 + l15;             // q row 0..63
        const int qc   = (ql < LQ) ? ql : (LQ - 1);
        const int qidx = Qi[b * LQ + qc];
        const float* qrow = (const float*)Wq + (size_t)qidx * DIM + g * 8;
        #pragma unroll
        for (int ks = 0; ks < 4; ++ks) {
            const float4 f0 = *(const float4*)(qrow + ks * 32);
            const float4 f1 = *(const float4*)(qrow + ks * 32 + 4);
            union { bf16x8 v; uint16_t u[8]; } pk;
            pk.u[0] = (uint16_t)f2bf(f0.x); pk.u[1] = (uint16_t)f2bf(f0.y);
            pk.u[2] = (uint16_t)f2bf(f0.z); pk.u[3] = (uint16_t)f2bf(f0.w);
            pk.u[4] = (uint16_t)f2bf(f1.x); pk.u[5] = (uint16_t)f2bf(f1.y);
            pk.u[6] = (uint16_t)f2bf(f1.z); pk.u[7] = (uint16_t)f2bf(f1.w);
            afr[ks] = pk.v;
        }
    }
    __syncthreads();

    // ---- phase 1: logits = Q @ K^T via mfma_f32_16x16x32_bf16 (R5-proven) ------
    {
        #pragma unroll 1
        for (int n = h; n < 13; n += 2) {          // 7 or 6 n-tiles per wave
            const uint16_t* kbase = ksh + (size_t)(n * 16 + l15) * KSTR + g * 8;
            f32x4 acc = {0.f, 0.f, 0.f, 0.f};
            #pragma unroll
            for (int ks = 0; ks < 4; ++ks) {
                const bf16x8 bfr = *(const bf16x8*)(kbase + ks * 32);
                acc = __builtin_amdgcn_mfma_f32_16x16x32_bf16(afr[ks], bfr, acc, 0, 0, 0);
            }
            const int kcol = n * 16 + l15;
            #pragma unroll
            for (int r = 0; r < 4; ++r) {
                const int q = m * 16 + g * 4 + r;
                if (q < LQ && kcol < LK)
                    lgt[q * LSTR + kcol] = acc[r] * 0.08838834764831843f;  // 1/sqrt(128)
            }
        }
    }
    __syncthreads();   // after this, ksh region is dead -> reused as vsh

    // ---- phase 2a: stage V transposed into (former ksh) region -----------------
    // Lane reads rows 8k8..8k8+7 as float2 (d = 2*lane, 2*lane+1): its .x values
    // across the 8 loads ARE column d's 8 k-entries -> one b128 write each.
    uint16_t* vsh = ukv;
    #pragma unroll
    for (int j = 0; j < 4; ++j) {
        const int k8 = w + NWAVE * j;              // 8-row block 0..27 (25..27 = pad)
        if (k8 < 28) {
            float2 vr[8];
            #pragma unroll
            for (int r = 0; r < 8; ++r) {
                const int k = k8 * 8 + r;
                if (k < LK) {
                    const int vidx = vix[k];
                    vr[r] = ((const float2*)((const float*)Wv + (size_t)vidx * DIM))[lane];
                } else vr[r] = make_float2(0.f, 0.f);
            }
            union { bf16x8 v; uint16_t u[8]; } px, py;
            #pragma unroll
            for (int r = 0; r < 8; ++r) {
                px.u[r] = (uint16_t)f2bf(vr[r].x);
                py.u[r] = (uint16_t)f2bf(vr[r].y);
            }
            *(bf16x8*)(vsh + (size_t)(2 * lane)     * VSTR + k8 * 8) = px.v;
            *(bf16x8*)(vsh + (size_t)(2 * lane + 1) * VSTR + k8 * 8) = py.v;
        }
    }

    // ---- phase 2b: weight = softmax_k(logit + eps) -> pwgt (bf16, zero-padded) -
    for (int q = w; q < 64; q += NWAVE) {
        if (q < LQ) {
            float z[4];
            float mx = -INFINITY;
            #pragma unroll
            for (int i = 0; i < 4; ++i) {
                const int k = i * 64 + lane;
                if (k < LK) {
                    const float e = ((const float*)ep)[(size_t)(b * LQ + q) * LK + k];
                    z[i] = lgt[q * LSTR + k] + e;
                    mx = fmaxf(mx, z[i]);
                } else z[i] = -INFINITY;
            }
            #pragma unroll
            for (int off = 32; off > 0; off >>= 1) mx = fmaxf(mx, __shfl_xor(mx, off));
            float e4[4]; float s = 0.f;
            #pragma unroll
            for (int i = 0; i < 4; ++i) {
                e4[i] = (i * 64 + lane < LK) ? __expf(z[i] - mx) : 0.f;
                s += e4[i];
            }
            #pragma unroll
            for (int off = 32; off > 0; off >>= 1) s += __shfl_xor(s, off);
            const float inv = 1.0f / s;
            #pragma unroll
            for (int i = 0; i < 4; ++i) {
                const int k = i * 64 + lane;
                if (k < PSTR)
                    pwgt[q * PSTR + k] = (k < LK) ? (uint16_t)f2bf(e4[i] * inv) : (uint16_t)0;
            }
        } else {
            #pragma unroll
            for (int i = 0; i < 4; ++i) {
                const int k = i * 64 + lane;
                if (k < PSTR) pwgt[q * PSTR + k] = 0;
            }
        }
    }
    __syncthreads();

    // ---- phase 3: context = P @ V via MFMA (same fragment layout as phase 1) ---
    f32x4 acc[4] = {{0.f,0.f,0.f,0.f},{0.f,0.f,0.f,0.f},{0.f,0.f,0.f,0.f},{0.f,0.f,0.f,0.f}};
    #pragma unroll
    for (int kt = 0; kt < NKT3; ++kt) {
        const bf16x8 a = *(const bf16x8*)(pwgt + (size_t)(m * 16 + l15) * PSTR + kt * 32 + g * 8);
        #pragma unroll
        for (int t = 0; t < 4; ++t) {
            const int d = (h * 4 + t) * 16 + l15;
            const bf16x8 bv = *(const bf16x8*)(vsh + (size_t)d * VSTR + kt * 32 + g * 8);
            acc[t] = __builtin_amdgcn_mfma_f32_16x16x32_bf16(a, bv, acc[t], 0, 0, 0);
        }
    }

    // ---- layernorm: in-wave 16-lane reduce (64 d's) + cross-wave partials ------
    float s1[4], s2[4];
    #pragma unroll
    for (int r = 0; r < 4; ++r) {
        s1[r] = acc[0][r] + acc[1][r] + acc[2][r] + acc[3][r];
        s2[r] = acc[0][r]*acc[0][r] + acc[1][r]*acc[1][r]
              + acc[2][r]*acc[2][r] + acc[3][r]*acc[3][r];
        #pragma unroll
        for (int off = 1; off < 16; off <<= 1) {
            s1[r] += __shfl_xor(s1[r], off);
            s2[r] += __shfl_xor(s2[r], off);
        }
    }
    if (l15 == 0) {
        #pragma unroll
        for (int r = 0; r < 4; ++r)
            part[(m * 16 + g * 4 + r) * 2 + h] = make_float2(s1[r], s2[r]);
    }
    __syncthreads();

    float* outf = (float*)out;
    #pragma unroll
    for (int r = 0; r < 4; ++r) {
        const int q = m * 16 + g * 4 + r;
        const float2 oth = part[q * 2 + (h ^ 1)];
        const float t1 = s1[r] + oth.x;
        const float t2 = s2[r] + oth.y;
        const float mu = t1 * (1.0f / DIM);
        float var = t2 * (1.0f / DIM) - mu * mu;
        var = fmaxf(var, 0.f);
        const float rs = rsqrtf(var + 1e-5f);
        if (q < LQ) {
            #pragma unroll
            for (int t = 0; t < 4; ++t) {
                const int d = (h * 4 + t) * 16 + l15;
                const float gv = ((const float*)gm)[d];
                const float bv = ((const float*)bt)[d];
                outf[(size_t)(b * LQ + q) * DIM + d] = (acc[t][r] - mu) * rs * gv + bv;
            }
        }
    }
}

// ---------------------------------------------------------------------------
// bf16 path — retained for probe completeness (not executed on this dataset).
// R5 structure: VALU dot-product phase 1, pipelined VALU phase 3.
// ---------------------------------------------------------------------------
__device__ __forceinline__ void run_bf16(
    int b,
    const int* __restrict__ Qi, const int* __restrict__ Ki, const int* __restrict__ Vi,
    const void* __restrict__ Wq, const void* __restrict__ Wk, const void* __restrict__ Wv,
    const void* __restrict__ gm, const void* __restrict__ bt, const void* __restrict__ ep,
    void* __restrict__ out, float* __restrict__ lds, int* __restrict__ vix)
{
    const int tid  = threadIdx.x;
    const int w    = tid >> 6;
    const int lane = tid & 63;

    for (int i = tid; i < LK; i += NTHR) vix[i] = Vi[b * LK + i];

    {
        const int ql   = (lane < LQ) ? lane : (LQ - 1);
        const int qidx = Qi[b * LQ + ql];
        const uint4* qrow = (const uint4*)((const uint16_t*)Wq + (size_t)qidx * DIM);
        const int k0 = w * KPW;

        int kidx[KPW];
        #pragma unroll
        for (int kk = 0; kk < KPW; ++kk) kidx[kk] = Ki[b * LK + k0 + kk];
        float acc[KPW];
        #pragma unroll
        for (int kk = 0; kk < KPW; ++kk) acc[kk] = 0.f;

        #pragma unroll 1
        for (int hh = 0; hh < DIM / 8; ++hh) {
            const uint4 qc = qrow[hh];
            const float a0 = bflo(qc.x), a1 = bfhi(qc.x);
            const float a2 = bflo(qc.y), a3 = bfhi(qc.y);
            const float a4 = bflo(qc.z), a5 = bfhi(qc.z);
            const float a6 = bflo(qc.w), a7 = bfhi(qc.w);
            #pragma unroll
            for (int kk = 0; kk < KPW; ++kk) {
                const uint4 t = ((const uint4*)((const uint16_t*)Wk + (size_t)kidx[kk] * DIM))[hh];
                float a = acc[kk];
                a = fmaf(a0, bflo(t.x), a);
                a = fmaf(a1, bfhi(t.x), a);
                a = fmaf(a2, bflo(t.y), a);
                a = fmaf(a3, bfhi(t.y), a);
                a = fmaf(a4, bflo(t.z), a);
                a = fmaf(a5, bfhi(t.z), a);
                a = fmaf(a6, bflo(t.w), a);
                a = fmaf(a7, bfhi(t.w), a);
                acc[kk] = a;
            }
        }
        if (lane < LQ) {
            #pragma unroll
            for (int kk = 0; kk < KPW; ++kk)
                lds[lane * LSTR + (k0 + kk)] = acc[kk] * 0.08838834764831843f;
        }
    }
    __syncthreads();

    for (int q = w; q < LQ; q += NWAVE) {
        float z[4];
        float mx = -INFINITY;
        #pragma unroll
        for (int i = 0; i < 4; ++i) {
            const int k = i * 64 + lane;
            if (k < LK) {
                const float e = bflo((uint32_t)((const uint16_t*)ep)[(size_t)(b*LQ+q)*LK + k]);
                z[i] = lds[q * LSTR + k] + e;
                mx = fmaxf(mx, z[i]);
            } else z[i] = -INFINITY;
        }
        #pragma unroll
        for (int off = 32; off > 0; off >>= 1) mx = fmaxf(mx, __shfl_xor(mx, off));
        float e4[4]; float s = 0.f;
        #pragma unroll
        for (int i = 0; i < 4; ++i) {
            e4[i] = (i * 64 + lane < LK) ? __expf(z[i] - mx) : 0.f;
            s += e4[i];
        }
        #pragma unroll
        for (int off = 32; off > 0; off >>= 1) s += __shfl_xor(s, off);
        const float inv = 1.0f / s;
        #pragma unroll
        for (int i = 0; i < 4; ++i) {
            const int k = i * 64 + lane;
            if (k < LK) lds[q * LSTR + k] = e4[i] * inv;
        }
    }
    __syncthreads();

    float c0[7], c1[7];
    #pragma unroll
    for (int qi = 0; qi < 7; ++qi) { c0[qi] = 0.f; c1[qi] = 0.f; }

    int rowq[7];
    #pragma unroll
    for (int qi = 0; qi < 7; ++qi) {
        const int q = w + 8 * qi;
        rowq[qi] = (q < LQ) ? q : (LQ - 1);
    }

    const uint16_t* Wvh = (const uint16_t*)Wv;

    auto load_grp = [&](uint32_t (&f)[VG], int kg) {
        #pragma unroll
        for (int u = 0; u < VG; ++u) {
            const int vidx = vix[kg * VG + u];
            f[u] = ((const uint32_t*)(Wvh + (size_t)vidx * DIM))[lane];
        }
    };
    auto consume_grp = [&](const uint32_t (&f)[VG], int kg) {
        #pragma unroll
        for (int u = 0; u < VG; ++u) {
            const int k = kg * VG + u;
            const float v0 = bflo(f[u]), v1 = bfhi(f[u]);
            #pragma unroll
            for (int qi = 0; qi < 7; ++qi) {
                const float wt = lds[rowq[qi] * LSTR + k];
                c0[qi] = fmaf(wt, v0, c0[qi]);
                c1[qi] = fmaf(wt, v1, c1[qi]);
            }
        }
    };

    uint32_t fA[VG], fB[VG];
    load_grp(fA, 0);
    #pragma unroll 1
    for (int kg = 0; kg < NG - 1; kg += 2) {
        load_grp(fB, kg + 1);
        consume_grp(fA, kg);
        load_grp(fA, kg + 2);
        consume_grp(fB, kg + 1);
    }
    consume_grp(fA, NG - 1);

    const uint32_t gu = ((const uint32_t*)gm)[lane];
    const uint32_t bu = ((const uint32_t*)bt)[lane];
    const float g0 = bflo(gu), g1 = bfhi(gu);
    const float be0 = bflo(bu), be1 = bfhi(bu);

    #pragma unroll
    for (int qi = 0; qi < 7; ++qi) {
        const int q = w + 8 * qi;
        if (q < LQ) {
            float s1 = c0[qi] + c1[qi];
            float s2 = c0[qi]*c0[qi] + c1[qi]*c1[qi];
            #pragma unroll
            for (int off = 32; off > 0; off >>= 1) {
                s1 += __shfl_xor(s1, off);
                s2 += __shfl_xor(s2, off);
            }
            const float mu = s1 * (1.0f / DIM);
            float var = s2 * (1.0f / DIM) - mu * mu;
            var = fmaxf(var, 0.f);
            const float rs = rsqrtf(var + 1e-5f);
            const float y0 = (c0[qi] - mu) * rs * g0 + be0;
            const float y1 = (c1[qi] - mu) * rs * g1 + be1;
            ((uint32_t*)out)[(size_t)(b*LQ+q) * (DIM/2) + lane] = f2bf(y0) | (f2bf(y1) << 16);
        }
    }
}

__global__ __launch_bounds__(NTHR, 1) void fused_attn_ln(
    const int* __restrict__ Qi, const int* __restrict__ Ki, const int* __restrict__ Vi,
    const void* __restrict__ Wq, const void* __restrict__ Wk, const void* __restrict__ Wv,
    const void* __restrict__ gm, const void* __restrict__ bt, const void* __restrict__ ep,
    void* __restrict__ out)
{
    __shared__ __align__(16) uint16_t ukv[UKV];        // K rows, then V^T (58.0 KB)
    __shared__ __align__(16) float    lgt[LQ * LSTR];  // logits f32        (40.8 KB)
    __shared__ __align__(16) uint16_t pwgt[64 * PSTR]; // weights bf16      (29.7 KB)
    __shared__ float2 part[64 * 2];                    // LN partials        (1.0 KB)
    __shared__ int vix[LK];                            // V indices          (0.8 KB)
    // total ~130.3 KB < 160 KB/CU -> 1 block/CU (grid 256 = CU count)

    const int b = blockIdx.x;

    // Dtype probe (same as all green rounds). On THIS dataset it selects f32.
    const uint32_t* probe = (const uint32_t*)Wq;
    int c = 0;
    #pragma unroll
    for (int i = 0; i < 64; ++i) {
        float f = bflo(probe[i]);
        c += (fabsf(f) < 1.0f) ? 1 : 0;
    }
    if (c >= 48) run_bf16(b, Qi, Ki, Vi, Wq, Wk, Wv, gm, bt, ep, out, lgt, vix);
    else         run_f32 (b, Qi, Ki, Vi, Wq, Wk, Wv, gm, bt, ep, out,
                          lgt, ukv, pwgt, part, vix);
}

extern "C" void kernel_launch(void* const* d_in, const int* in_sizes, int n_in,
                              void* d_out, int out_size, void* d_ws, size_t ws_size,
                              hipStream_t stream)
{
    (void)in_sizes; (void)n_in; (void)out_size; (void)d_ws; (void)ws_size;
    fused_attn_ln<<<NB, NTHR, 0, stream>>>(
        (const int*)d_in[0], (const int*)d_in[1], (const int*)d_in[2],
        d_in[3], d_in[4], d_in[5], d_in[6], d_in[7], d_in[8], d_out);
}

// Round 8
// 172.253 us; speedup vs baseline: 1.1232x; 1.0297x over previous
//
#include <hip/hip_runtime.h>
#include <hip/hip_bf16.h>
#include <cstdint>

namespace {
constexpr int NB    = 256;   // batches; grid 256, 1 block/batch
constexpr int LQ    = 50;
constexpr int LK    = 200;
constexpr int DIM   = 128;
constexpr int NWAVE = 8;
constexpr int NTHR  = NWAVE * 64;
constexpr int KSTR  = 136;   // ksh bf16 row stride (R5-proven)
constexpr int NKR   = 208;   // staged K rows (13 n-tiles x 16, zero-padded)
constexpr int PSTR  = 232;   // pwgt bf16 row stride
constexpr int VSTR  = 232;   // vsh  bf16 row stride
constexpr int NKT3  = 7;     // phase-3 k-tiles (224 = 7*32)
constexpr int LSTR  = 204;   // fallback-path f32 stride
constexpr int KPW   = LK / NWAVE;   // fallback only
constexpr int VG    = 8;            // fallback only
constexpr int NG    = LK / VG;      // fallback only
constexpr float SCL = 0.08838834764831843f;  // 1/sqrt(128)
}

typedef __attribute__((ext_vector_type(8))) short bf16x8;   // 8 bf16 = 4 VGPR
typedef __attribute__((ext_vector_type(4))) float f32x4;

__device__ __forceinline__ float bflo(uint32_t u) { return __uint_as_float(u << 16); }
__device__ __forceinline__ float bfhi(uint32_t u) { return __uint_as_float(u & 0xFFFF0000u); }
__device__ __forceinline__ uint32_t f2bf(float f) {
    uint32_t x = __float_as_uint(f);
    return (x + 0x7FFFu + ((x >> 16) & 1u)) >> 16;   // RNE
}

// ---------------------------------------------------------------------------
// f32 path — THE path that executes on this dataset.
// R8: ALL long-latency global reads (K rows, V rows, V indices, eps noise, Q
// rows) issue in phase 0 as one giant independent burst; phases 1-3 are then
// pure LDS/VALU/MFMA. Enabled by (a) vsh owning its own region (lgt deleted:
// phase 1 stores logits bf16 directly into pwgt, overwritten by softmax in
// place), (b) eps prefetched to registers, (c) V indices read as wave-uniform
// int4 (no vix round-trip). 1/sqrt(128) folded into Q fragments.
// ---------------------------------------------------------------------------
__device__ __forceinline__ void run_f32(
    int b,
    const int* __restrict__ Qi, const int* __restrict__ Ki, const int* __restrict__ Vi,
    const void* __restrict__ Wq, const void* __restrict__ Wk, const void* __restrict__ Wv,
    const void* __restrict__ gm, const void* __restrict__ bt, const void* __restrict__ ep,
    void* __restrict__ out, uint16_t* __restrict__ ksh, uint16_t* __restrict__ vsh,
    uint16_t* __restrict__ pwgt, float2* __restrict__ part)
{
    const int tid  = threadIdx.x;
    const int w    = tid >> 6;
    const int lane = tid & 63;
    const int l15  = lane & 15;
    const int g    = lane >> 4;      // k-group 0..3
    const int m    = w >> 1;         // m-tile 0..3 (q rows m*16..m*16+15)
    const int h    = w & 1;          // phase-1 n-parity / phase-3 d-half

    // ======================= phase 0: the load burst ========================
    // --- Q fragments (pre-scaled by 1/sqrt(128)) ---
    bf16x8 afr[4];
    {
        const int ql   = m * 16 + l15;
        const int qc   = (ql < LQ) ? ql : (LQ - 1);
        const int qidx = Qi[b * LQ + qc];
        const float* qrow = (const float*)Wq + (size_t)qidx * DIM + g * 8;
        #pragma unroll
        for (int ks = 0; ks < 4; ++ks) {
            const float4 f0 = *(const float4*)(qrow + ks * 32);
            const float4 f1 = *(const float4*)(qrow + ks * 32 + 4);
            union { bf16x8 v; uint16_t u[8]; } pk;
            pk.u[0] = (uint16_t)f2bf(f0.x * SCL); pk.u[1] = (uint16_t)f2bf(f0.y * SCL);
            pk.u[2] = (uint16_t)f2bf(f0.z * SCL); pk.u[3] = (uint16_t)f2bf(f0.w * SCL);
            pk.u[4] = (uint16_t)f2bf(f1.x * SCL); pk.u[5] = (uint16_t)f2bf(f1.y * SCL);
            pk.u[6] = (uint16_t)f2bf(f1.z * SCL); pk.u[7] = (uint16_t)f2bf(f1.w * SCL);
            afr[ks] = pk.v;
        }
    }

    // --- K rows -> ksh (bf16, coalesced, rows 200..207 zero) ---
    #pragma unroll
    for (int j = 0; j < NKR / NWAVE; ++j) {        // 26 K rows per wave
        const int r = w + NWAVE * j;
        uint32_t v = 0u;
        if (r < LK) {
            const int kidx = Ki[b * LK + r];
            const float2 f = ((const float2*)((const float*)Wk + (size_t)kidx * DIM))[lane];
            v = f2bf(f.x) | (f2bf(f.y) << 16);
        }
        *(uint32_t*)(ksh + (size_t)r * KSTR + 2 * lane) = v;
    }

    // --- V rows -> vsh TRANSPOSED (bf16). Lane's float2 column IS a d-column. -
    #pragma unroll
    for (int j = 0; j < 4; ++j) {
        const int k8 = w + NWAVE * j;              // 8-row block 0..31
        if (k8 < 25) {                             // k = k8*8 .. k8*8+7 all < 200
            const int4 ia = *(const int4*)(Vi + b * LK + k8 * 8);
            const int4 ib = *(const int4*)(Vi + b * LK + k8 * 8 + 4);
            float2 vr[8];
            vr[0] = ((const float2*)((const float*)Wv + (size_t)ia.x * DIM))[lane];
            vr[1] = ((const float2*)((const float*)Wv + (size_t)ia.y * DIM))[lane];
            vr[2] = ((const float2*)((const float*)Wv + (size_t)ia.z * DIM))[lane];
            vr[3] = ((const float2*)((const float*)Wv + (size_t)ia.w * DIM))[lane];
            vr[4] = ((const float2*)((const float*)Wv + (size_t)ib.x * DIM))[lane];
            vr[5] = ((const float2*)((const float*)Wv + (size_t)ib.y * DIM))[lane];
            vr[6] = ((const float2*)((const float*)Wv + (size_t)ib.z * DIM))[lane];
            vr[7] = ((const float2*)((const float*)Wv + (size_t)ib.w * DIM))[lane];
            union { bf16x8 v; uint16_t u[8]; } px, py;
            #pragma unroll
            for (int r = 0; r < 8; ++r) {
                px.u[r] = (uint16_t)f2bf(vr[r].x);
                py.u[r] = (uint16_t)f2bf(vr[r].y);
            }
            *(bf16x8*)(vsh + (size_t)(2 * lane)     * VSTR + k8 * 8) = px.v;
            *(bf16x8*)(vsh + (size_t)(2 * lane + 1) * VSTR + k8 * 8) = py.v;
        } else if (k8 < 28) {                      // zero-pad cols 200..223
            const bf16x8 z = {0,0,0,0,0,0,0,0};
            *(bf16x8*)(vsh + (size_t)(2 * lane)     * VSTR + k8 * 8) = z;
            *(bf16x8*)(vsh + (size_t)(2 * lane + 1) * VSTR + k8 * 8) = z;
        }
    }

    // --- eps noise -> registers (wave w handles q = w, w+8, ..., w+48) ---
    float er[7][4];
    #pragma unroll
    for (int j = 0; j < 7; ++j) {
        const int q = w + 8 * j;
        if (q < LQ) {
            #pragma unroll
            for (int i = 0; i < 4; ++i) {
                const int k = i * 64 + lane;
                er[j][i] = (k < LK) ? ((const float*)ep)[(size_t)(b * LQ + q) * LK + k] : 0.f;
            }
        } else {
            #pragma unroll
            for (int i = 0; i < 4; ++i) er[j][i] = 0.f;
        }
    }
    __syncthreads();

    // ---- phase 1: logits = Q @ K^T via MFMA -> pwgt (bf16, in place) ----------
    {
        #pragma unroll 1
        for (int n = h; n < 13; n += 2) {          // 7 or 6 n-tiles per wave
            const uint16_t* kbase = ksh + (size_t)(n * 16 + l15) * KSTR + g * 8;
            f32x4 acc = {0.f, 0.f, 0.f, 0.f};
            #pragma unroll
            for (int ks = 0; ks < 4; ++ks) {
                const bf16x8 bfr = *(const bf16x8*)(kbase + ks * 32);
                acc = __builtin_amdgcn_mfma_f32_16x16x32_bf16(afr[ks], bfr, acc, 0, 0, 0);
            }
            const int kcol = n * 16 + l15;
            #pragma unroll
            for (int r = 0; r < 4; ++r) {
                const int q = m * 16 + g * 4 + r;
                if (q < LQ && kcol < LK)
                    pwgt[q * PSTR + kcol] = (uint16_t)f2bf(acc[r]);
            }
        }
    }
    __syncthreads();

    // ---- phase 2: softmax_k(logit + eps) in place in pwgt (bf16 out) ----------
    #pragma unroll
    for (int j = 0; j < 8; ++j) {
        const int q = w + 8 * j;
        if (j < 7 && q < LQ) {
            float z[4];
            float mx = -INFINITY;
            #pragma unroll
            for (int i = 0; i < 4; ++i) {
                const int k = i * 64 + lane;
                if (k < LK) {
                    z[i] = bflo((uint32_t)pwgt[q * PSTR + k]) + er[j][i];
                    mx = fmaxf(mx, z[i]);
                } else z[i] = -INFINITY;
            }
            #pragma unroll
            for (int off = 32; off > 0; off >>= 1) mx = fmaxf(mx, __shfl_xor(mx, off));
            float e4[4]; float s = 0.f;
            #pragma unroll
            for (int i = 0; i < 4; ++i) {
                e4[i] = (i * 64 + lane < LK) ? __expf(z[i] - mx) : 0.f;
                s += e4[i];
            }
            #pragma unroll
            for (int off = 32; off > 0; off >>= 1) s += __shfl_xor(s, off);
            const float inv = 1.0f / s;
            #pragma unroll
            for (int i = 0; i < 4; ++i) {
                const int k = i * 64 + lane;
                if (k < PSTR)
                    pwgt[q * PSTR + k] = (k < LK) ? (uint16_t)f2bf(e4[i] * inv) : (uint16_t)0;
            }
        } else if (q >= LQ && q < 64) {
            #pragma unroll
            for (int i = 0; i < 4; ++i) {
                const int k = i * 64 + lane;
                if (k < PSTR) pwgt[q * PSTR + k] = 0;
            }
        }
    }
    __syncthreads();

    // ---- phase 3: context = P @ V^T via MFMA (R7-proven layout) ---------------
    f32x4 acc[4] = {{0.f,0.f,0.f,0.f},{0.f,0.f,0.f,0.f},{0.f,0.f,0.f,0.f},{0.f,0.f,0.f,0.f}};
    #pragma unroll
    for (int kt = 0; kt < NKT3; ++kt) {
        const bf16x8 a = *(const bf16x8*)(pwgt + (size_t)(m * 16 + l15) * PSTR + kt * 32 + g * 8);
        #pragma unroll
        for (int t = 0; t < 4; ++t) {
            const int d = (h * 4 + t) * 16 + l15;
            const bf16x8 bv = *(const bf16x8*)(vsh + (size_t)d * VSTR + kt * 32 + g * 8);
            acc[t] = __builtin_amdgcn_mfma_f32_16x16x32_bf16(a, bv, acc[t], 0, 0, 0);
        }
    }

    // ---- layernorm: in-wave 16-lane reduce + cross-wave partial exchange ------
    float s1[4], s2[4];
    #pragma unroll
    for (int r = 0; r < 4; ++r) {
        s1[r] = acc[0][r] + acc[1][r] + acc[2][r] + acc[3][r];
        s2[r] = acc[0][r]*acc[0][r] + acc[1][r]*acc[1][r]
              + acc[2][r]*acc[2][r] + acc[3][r]*acc[3][r];
        #pragma unroll
        for (int off = 1; off < 16; off <<= 1) {
            s1[r] += __shfl_xor(s1[r], off);
            s2[r] += __shfl_xor(s2[r], off);
        }
    }
    if (l15 == 0) {
        #pragma unroll
        for (int r = 0; r < 4; ++r)
            part[(m * 16 + g * 4 + r) * 2 + h] = make_float2(s1[r], s2[r]);
    }
    __syncthreads();

    float* outf = (float*)out;
    #pragma unroll
    for (int r = 0; r < 4; ++r) {
        const int q = m * 16 + g * 4 + r;
        const float2 oth = part[q * 2 + (h ^ 1)];
        const float t1 = s1[r] + oth.x;
        const float t2 = s2[r] + oth.y;
        const float mu = t1 * (1.0f / DIM);
        float var = t2 * (1.0f / DIM) - mu * mu;
        var = fmaxf(var, 0.f);
        const float rs = rsqrtf(var + 1e-5f);
        if (q < LQ) {
            #pragma unroll
            for (int t = 0; t < 4; ++t) {
                const int d = (h * 4 + t) * 16 + l15;
                const float gv = ((const float*)gm)[d];
                const float bv = ((const float*)bt)[d];
                outf[(size_t)(b * LQ + q) * DIM + d] = (acc[t][r] - mu) * rs * gv + bv;
            }
        }
    }
}

// ---------------------------------------------------------------------------
// bf16 path — retained for probe completeness (not executed on this dataset).
// R5 structure: VALU dot-product phase 1, pipelined VALU phase 3.
// ---------------------------------------------------------------------------
__device__ __forceinline__ void run_bf16(
    int b,
    const int* __restrict__ Qi, const int* __restrict__ Ki, const int* __restrict__ Vi,
    const void* __restrict__ Wq, const void* __restrict__ Wk, const void* __restrict__ Wv,
    const void* __restrict__ gm, const void* __restrict__ bt, const void* __restrict__ ep,
    void* __restrict__ out, float* __restrict__ lds, int* __restrict__ vix)
{
    const int tid  = threadIdx.x;
    const int w    = tid >> 6;
    const int lane = tid & 63;

    for (int i = tid; i < LK; i += NTHR) vix[i] = Vi[b * LK + i];

    {
        const int ql   = (lane < LQ) ? lane : (LQ - 1);
        const int qidx = Qi[b * LQ + ql];
        const uint4* qrow = (const uint4*)((const uint16_t*)Wq + (size_t)qidx * DIM);
        const int k0 = w * KPW;

        int kidx[KPW];
        #pragma unroll
        for (int kk = 0; kk < KPW; ++kk) kidx[kk] = Ki[b * LK + k0 + kk];
        float acc[KPW];
        #pragma unroll
        for (int kk = 0; kk < KPW; ++kk) acc[kk] = 0.f;

        #pragma unroll 1
        for (int hh = 0; hh < DIM / 8; ++hh) {
            const uint4 qc = qrow[hh];
            const float a0 = bflo(qc.x), a1 = bfhi(qc.x);
            const float a2 = bflo(qc.y), a3 = bfhi(qc.y);
            const float a4 = bflo(qc.z), a5 = bfhi(qc.z);
            const float a6 = bflo(qc.w), a7 = bfhi(qc.w);
            #pragma unroll
            for (int kk = 0; kk < KPW; ++kk) {
                const uint4 t = ((const uint4*)((const uint16_t*)Wk + (size_t)kidx[kk] * DIM))[hh];
                float a = acc[kk];
                a = fmaf(a0, bflo(t.x), a);
                a = fmaf(a1, bfhi(t.x), a);
                a = fmaf(a2, bflo(t.y), a);
                a = fmaf(a3, bfhi(t.y), a);
                a = fmaf(a4, bflo(t.z), a);
                a = fmaf(a5, bfhi(t.z), a);
                a = fmaf(a6, bflo(t.w), a);
                a = fmaf(a7, bfhi(t.w), a);
                acc[kk] = a;
            }
        }
        if (lane < LQ) {
            #pragma unroll
            for (int kk = 0; kk < KPW; ++kk)
                lds[lane * LSTR + (k0 + kk)] = acc[kk] * SCL;
        }
    }
    __syncthreads();

    for (int q = w; q < LQ; q += NWAVE) {
        float z[4];
        float mx = -INFINITY;
        #pragma unroll
        for (int i = 0; i < 4; ++i) {
            const int k = i * 64 + lane;
            if (k < LK) {
                const float e = bflo((uint32_t)((const uint16_t*)ep)[(size_t)(b*LQ+q)*LK + k]);
                z[i] = lds[q * LSTR + k] + e;
                mx = fmaxf(mx, z[i]);
            } else z[i] = -INFINITY;
        }
        #pragma unroll
        for (int off = 32; off > 0; off >>= 1) mx = fmaxf(mx, __shfl_xor(mx, off));
        float e4[4]; float s = 0.f;
        #pragma unroll
        for (int i = 0; i < 4; ++i) {
            e4[i] = (i * 64 + lane < LK) ? __expf(z[i] - mx) : 0.f;
            s += e4[i];
        }
        #pragma unroll
        for (int off = 32; off > 0; off >>= 1) s += __shfl_xor(s, off);
        const float inv = 1.0f / s;
        #pragma unroll
        for (int i = 0; i < 4; ++i) {
            const int k = i * 64 + lane;
            if (k < LK) lds[q * LSTR + k] = e4[i] * inv;
        }
    }
    __syncthreads();

    float c0[7], c1[7];
    #pragma unroll
    for (int qi = 0; qi < 7; ++qi) { c0[qi] = 0.f; c1[qi] = 0.f; }

    int rowq[7];
    #pragma unroll
    for (int qi = 0; qi < 7; ++qi) {
        const int q = w + 8 * qi;
        rowq[qi] = (q < LQ) ? q : (LQ - 1);
    }

    const uint16_t* Wvh = (const uint16_t*)Wv;

    auto load_grp = [&](uint32_t (&f)[VG], int kg) {
        #pragma unroll
        for (int u = 0; u < VG; ++u) {
            const int vidx = vix[kg * VG + u];
            f[u] = ((const uint32_t*)(Wvh + (size_t)vidx * DIM))[lane];
        }
    };
    auto consume_grp = [&](const uint32_t (&f)[VG], int kg) {
        #pragma unroll
        for (int u = 0; u < VG; ++u) {
            const int k = kg * VG + u;
            const float v0 = bflo(f[u]), v1 = bfhi(f[u]);
            #pragma unroll
            for (int qi = 0; qi < 7; ++qi) {
                const float wt = lds[rowq[qi] * LSTR + k];
                c0[qi] = fmaf(wt, v0, c0[qi]);
                c1[qi] = fmaf(wt, v1, c1[qi]);
            }
        }
    };

    uint32_t fA[VG], fB[VG];
    load_grp(fA, 0);
    #pragma unroll 1
    for (int kg = 0; kg < NG - 1; kg += 2) {
        load_grp(fB, kg + 1);
        consume_grp(fA, kg);
        load_grp(fA, kg + 2);
        consume_grp(fB, kg + 1);
    }
    consume_grp(fA, NG - 1);

    const uint32_t gu = ((const uint32_t*)gm)[lane];
    const uint32_t bu = ((const uint32_t*)bt)[lane];
    const float g0 = bflo(gu), g1 = bfhi(gu);
    const float be0 = bflo(bu), be1 = bfhi(bu);

    #pragma unroll
    for (int qi = 0; qi < 7; ++qi) {
        const int q = w + 8 * qi;
        if (q < LQ) {
            float s1 = c0[qi] + c1[qi];
            float s2 = c0[qi]*c0[qi] + c1[qi]*c1[qi];
            #pragma unroll
            for (int off = 32; off > 0; off >>= 1) {
                s1 += __shfl_xor(s1, off);
                s2 += __shfl_xor(s2, off);
            }
            const float mu = s1 * (1.0f / DIM);
            float var = s2 * (1.0f / DIM) - mu * mu;
            var = fmaxf(var, 0.f);
            const float rs = rsqrtf(var + 1e-5f);
            const float y0 = (c0[qi] - mu) * rs * g0 + be0;
            const float y1 = (c1[qi] - mu) * rs * g1 + be1;
            ((uint32_t*)out)[(size_t)(b*LQ+q) * (DIM/2) + lane] = f2bf(y0) | (f2bf(y1) << 16);
        }
    }
}

__global__ __launch_bounds__(NTHR, 1) void fused_attn_ln(
    const int* __restrict__ Qi, const int* __restrict__ Ki, const int* __restrict__ Vi,
    const void* __restrict__ Wq, const void* __restrict__ Wk, const void* __restrict__ Wv,
    const void* __restrict__ gm, const void* __restrict__ bt, const void* __restrict__ ep,
    void* __restrict__ out)
{
    __shared__ __align__(16) uint16_t ksh[NKR * KSTR];  // K rows bf16      (56.6 KB)
    __shared__ __align__(16) uint16_t vsh[DIM * VSTR];  // V^T bf16         (59.4 KB)
    __shared__ __align__(16) uint16_t pwgt[64 * PSTR];  // logits->weights  (29.7 KB)
    __shared__ float2 part[64 * 2];                     // LN partials       (1.0 KB)
    __shared__ int vix[LK];                             // fallback only     (0.8 KB)
    // total ~147.5 KB < 160 KB/CU -> 1 block/CU (grid 256 = CU count)

    const int b = blockIdx.x;

    // Dtype probe (same as all green rounds). On THIS dataset it selects f32.
    const uint32_t* probe = (const uint32_t*)Wq;
    int c = 0;
    #pragma unroll
    for (int i = 0; i < 64; ++i) {
        float f = bflo(probe[i]);
        c += (fabsf(f) < 1.0f) ? 1 : 0;
    }
    if (c >= 48) run_bf16(b, Qi, Ki, Vi, Wq, Wk, Wv, gm, bt, ep, out,
                          (float*)vsh, vix);
    else         run_f32 (b, Qi, Ki, Vi, Wq, Wk, Wv, gm, bt, ep, out,
                          ksh, vsh, pwgt, part);
}

extern "C" void kernel_launch(void* const* d_in, const int* in_sizes, int n_in,
                              void* d_out, int out_size, void* d_ws, size_t ws_size,
                              hipStream_t stream)
{
    (void)in_sizes; (void)n_in; (void)out_size; (void)d_ws; (void)ws_size;
    fused_attn_ln<<<NB, NTHR, 0, stream>>>(
        (const int*)d_in[0], (const int*)d_in[1], (const int*)d_in[2],
        d_in[3], d_in[4], d_in[5], d_in[6], d_in[7], d_in[8], d_out);
}